// Round 4
// baseline (205.905 us; speedup 1.0000x reference)
//
#include <hip/hip_runtime.h>
#include <stdint.h>

// Toeplitz matvec = circular conv via batched 4096-pt radix-16 FFT.
// Per block: TWO real columns packed z = x[:,e0] + i*x[:,e0+1].
// v4: stage-1 fused with global load (zero-pad pruned), stage-5 fused with
// global store (output pruned), twiddles from precomputed tables (no serial
// cmul chains). 4 LDS round-trips instead of 6.
// ws: [0,32MiB) xT bf16 [8][1024][2048]; then tw2, V2, tw4096 (float2[4096]
// each), tw256 (float2[256]).

#define B_ 8
#define N_ 2048
#define NF 4096
#define E_ 1024

#define BUFSZ (NF + (NF >> 5))          // 4224 float2, swizzled
__device__ __forceinline__ int P(int n) { return n + (n >> 5); }
#define PERM(r) ((((r) & 3) << 2) | ((r) >> 2))   // DFT16 reg<->index transpose

__device__ __forceinline__ unsigned short f32_to_bf16_rne(float f) {
    union { float f; unsigned int u; } cv; cv.f = f;
    unsigned int u = cv.u;
    u += 0x7fffu + ((u >> 16) & 1u);
    return (unsigned short)(u >> 16);
}
__device__ __forceinline__ float bf16_to_f32(unsigned short u) {
    union { unsigned int u; float f; } cv; cv.u = ((unsigned int)u) << 16; return cv.f;
}
__device__ __forceinline__ void cmul(float& ar, float& ai, float br, float bi) {
    float t = ar * br - ai * bi; ai = ar * bi + ai * br; ar = t;
}
__device__ __forceinline__ void cmulc(float& ar, float& ai, float br, float bi) {
    float t = ar * br + ai * bi; ai = ai * br - ar * bi; ar = t;   // a *= conj(b)
}

// DFT4, sg=-1 fwd, +1 inv.
__device__ __forceinline__ void dft4(float& x0r, float& x0i, float& x1r, float& x1i,
                                     float& x2r, float& x2i, float& x3r, float& x3i,
                                     float sg) {
    float t0r = x0r + x2r, t0i = x0i + x2i;
    float t1r = x0r - x2r, t1i = x0i - x2i;
    float t2r = x1r + x3r, t2i = x1i + x3i;
    float t3r = x1r - x3r, t3i = x1i - x3i;
    x0r = t0r + t2r; x0i = t0i + t2i;
    x2r = t0r - t2r; x2i = t0i - t2i;
    x1r = t1r - sg * t3i; x1i = t1i + sg * t3r;
    x3r = t1r + sg * t3i; x3i = t1i - sg * t3r;
}

template<int SG>
__device__ __forceinline__ void dft16_layer1(float* xr, float* xi) {
    const float sg = (float)SG;
#pragma unroll
    for (int n0 = 0; n0 < 4; ++n0)
        dft4(xr[n0], xi[n0], xr[n0 + 4], xi[n0 + 4],
             xr[n0 + 8], xi[n0 + 8], xr[n0 + 12], xi[n0 + 12], sg);
}
// upper 8 inputs (slots 8..15) known zero
template<int SG>
__device__ __forceinline__ void dft16_layer1_pad(float* xr, float* xi) {
    const float sg = (float)SG;
#pragma unroll
    for (int n0 = 0; n0 < 4; ++n0) {
        float ar = xr[n0], ai = xi[n0], br = xr[n0 + 4], bi = xi[n0 + 4];
        xr[n0]      = ar + br;       xi[n0]      = ai + bi;
        xr[n0 + 4]  = ar - sg * bi;  xi[n0 + 4]  = ai + sg * br;
        xr[n0 + 8]  = ar - br;       xi[n0 + 8]  = ai - bi;
        xr[n0 + 12] = ar + sg * bi;  xi[n0 + 12] = ai - sg * br;
    }
}
template<int SG>
__device__ __forceinline__ void dft16_twiddle(float* xr, float* xi) {
    const float sg = (float)SG;
    const float C1 = 0.923879532511286756f;
    const float S1 = 0.382683432365089772f;
    const float H  = 0.707106781186547524f;
    cmul(xr[5],  xi[5],  C1,  sg * S1);
    cmul(xr[9],  xi[9],  H,   sg * H);
    cmul(xr[13], xi[13], S1,  sg * C1);
    cmul(xr[6],  xi[6],  H,   sg * H);
    cmul(xr[10], xi[10], 0.f, sg);
    cmul(xr[14], xi[14], -H,  sg * H);
    cmul(xr[7],  xi[7],  S1,  sg * C1);
    cmul(xr[11], xi[11], -H,  sg * H);
    cmul(xr[15], xi[15], -C1, -sg * S1);
}
template<int SG>
__device__ __forceinline__ void dft16_layer2(float* xr, float* xi) {
    const float sg = (float)SG;
#pragma unroll
    for (int k1 = 0; k1 < 4; ++k1)
        dft4(xr[4 * k1], xi[4 * k1], xr[4 * k1 + 1], xi[4 * k1 + 1],
             xr[4 * k1 + 2], xi[4 * k1 + 2], xr[4 * k1 + 3], xi[4 * k1 + 3], sg);
}
template<int SG>
__device__ __forceinline__ void dft16(float* xr, float* xi) {
    dft16_layer1<SG>(xr, xi);
    dft16_twiddle<SG>(xr, xi);
    dft16_layer2<SG>(xr, xi);
}

// generic staged butterfly (kept for build_V only; serial chain, 1 block)
template<int INV, int L>
__device__ __forceinline__ void fft_stage(float2* buf, const float2* __restrict__ tw2, int t) {
    constexpr int Lq = L / 16;
    int g = t / Lq;
    int j = t - g * Lq;
    int base = g * L + j;
    float xr[16], xi[16];
#pragma unroll
    for (int r = 0; r < 16; ++r) {
        float2 v = buf[P(base + r * Lq)];
        xr[r] = v.x; xi[r] = v.y;
    }
    float2 w1 = tw2[j * (NF / L)];
    float w1r = w1.x, w1i = INV ? -w1.y : w1.y;
    if (INV) {
        float wr = 1.f, wi = 0.f;
#pragma unroll
        for (int r = 1; r < 16; ++r) { cmul(wr, wi, w1r, w1i); cmul(xr[r], xi[r], wr, wi); }
        dft16<1>(xr, xi);
#pragma unroll
        for (int r = 0; r < 16; ++r) {
            float2 v; v.x = xr[PERM(r)]; v.y = xi[PERM(r)];
            buf[P(base + r * Lq)] = v;
        }
    } else {
        dft16<-1>(xr, xi);
        { float2 v; v.x = xr[0]; v.y = xi[0]; buf[P(base)] = v; }
        float wr = 1.f, wi = 0.f;
#pragma unroll
        for (int r = 1; r < 16; ++r) {
            cmul(wr, wi, w1r, w1i);
            float yr = xr[PERM(r)], yi = xi[PERM(r)];
            cmul(yr, yi, wr, wi);
            float2 v; v.x = yr; v.y = yi;
            buf[P(base + r * Lq)] = v;
        }
    }
}

// ---------------- twiddle tables ---------------------------------------------
// blocks 0..15: tw2[k]=cis(-2pi k/4096) and tw4096[r*256+j]=cis(-2pi r j/4096)
// block 16:     tw256[r*16+j]=cis(-2pi r j/256)
__global__ __launch_bounds__(256) void build_tw(float2* tw2, float2* tw4096, float2* tw256) {
    const float TPI = -6.28318530717958647692f;
    int blk = blockIdx.x, t = threadIdx.x;
    if (blk < 16) {
        int k = blk * 256 + t;
        float s, c;
        __sincosf(TPI * (float)k * (1.f / 4096.f), &s, &c);
        float2 v; v.x = c; v.y = s;
        tw2[k] = v;
        int rj = (blk * t) & (NF - 1);
        __sincosf(TPI * (float)rj * (1.f / 4096.f), &s, &c);
        float2 w; w.x = c; w.y = s;
        tw4096[blk * 256 + t] = w;
    } else {
        int r = t >> 4, j = t & 15;
        float s, c;
        __sincosf(TPI * (float)(r * j) * (1.f / 256.f), &s, &c);
        float2 v; v.x = c; v.y = s;
        tw256[t] = v;
    }
}

// ---------------- V = DIF(a)/4096 in raw (digit-reversed) slots --------------
__global__ __launch_bounds__(256) void build_V(const float* __restrict__ pos,
                                               const float* __restrict__ zero,
                                               const float* __restrict__ neg,
                                               const float2* __restrict__ tw2,
                                               float2* __restrict__ V2) {
    __shared__ float2 buf[BUFSZ];
    int t = threadIdx.x;
#pragma unroll
    for (int it = 0; it < 16; ++it) {
        int n = t + 256 * it;
        float v;
        if (n == 0) v = zero[0];
        else if (n < N_) v = pos[n - 1];
        else if (n == N_) v = zero[0];
        else v = neg[n - (N_ + 1)];
        float2 c; c.x = v; c.y = 0.f;
        buf[P(n)] = c;
    }
    __syncthreads();
    fft_stage<0, 4096>(buf, tw2, t); __syncthreads();
    fft_stage<0, 256>(buf, tw2, t);  __syncthreads();
    fft_stage<0, 16>(buf, tw2, t);   __syncthreads();
    const float s = 1.f / (float)NF;
#pragma unroll
    for (int it = 0; it < 16; ++it) {
        int n = t + 256 * it;
        float2 c = buf[P(n)];
        c.x *= s; c.y *= s;
        V2[n] = c;
    }
}

// ---------------- x [b][j][e] fp32 -> xT [b][e][j] bf16 ----------------------
__global__ __launch_bounds__(256) void transpose_x(const float* __restrict__ x,
                                                   unsigned short* __restrict__ xT) {
    __shared__ float tile[64][66];
    int b  = blockIdx.z;
    int j0 = blockIdx.y * 64;
    int e0 = blockIdx.x * 64;
    int t  = threadIdx.x;

    int e4 = t & 15, jr = t >> 4;
#pragma unroll
    for (int it = 0; it < 4; ++it) {
        int j = jr + it * 16;
        const float4 v = *(const float4*)(x + ((size_t)(b * N_ + j0 + j) * E_) + e0 + e4 * 4);
        tile[e4 * 4 + 0][j] = v.x;
        tile[e4 * 4 + 1][j] = v.y;
        tile[e4 * 4 + 2][j] = v.z;
        tile[e4 * 4 + 3][j] = v.w;
    }
    __syncthreads();
    int j2 = (t & 31) * 2, er = t >> 5;
#pragma unroll
    for (int it = 0; it < 8; ++it) {
        int e = er + it * 8;
        float2 v = *(const float2*)&tile[e][j2];
        union { unsigned short s[2]; unsigned int u; } pk;
        pk.s[0] = f32_to_bf16_rne(v.x);
        pk.s[1] = f32_to_bf16_rne(v.y);
        *(unsigned int*)(xT + ((size_t)(b * E_ + e0 + e)) * N_ + j0 + j2) = pk.u;
    }
}

// ---------------- main: FFT-conv, one column pair per block ------------------
__global__ __launch_bounds__(256) void fft_conv(const unsigned short* __restrict__ xT,
                                                const float2* __restrict__ tw4096,
                                                const float2* __restrict__ tw256,
                                                const float2* __restrict__ V2,
                                                float* __restrict__ out) {
    __shared__ float2 buf[BUFSZ];
    int t = threadIdx.x;
    int bid = blockIdx.x;
    int xcd = bid & 7;
    int q = bid >> 3;
    int b = q >> 6;
    int e0 = (xcd * 64 + (q & 63)) * 2;

    const unsigned short* r0 = xT + ((size_t)(b * E_ + e0)) * N_;
    const unsigned short* r1 = r0 + N_;

    float xr[16], xi[16];

    // ---- Phase A: fwd L=4096, inputs straight from global; slots 8..15 zero
#pragma unroll
    for (int r = 0; r < 8; ++r) {
        int n = t + 256 * r;
        xr[r] = bf16_to_f32(r0[n]);
        xi[r] = bf16_to_f32(r1[n]);
    }
#pragma unroll
    for (int r = 8; r < 16; ++r) { xr[r] = 0.f; xi[r] = 0.f; }
    dft16_layer1_pad<-1>(xr, xi);
    dft16_twiddle<-1>(xr, xi);
    dft16_layer2<-1>(xr, xi);
    { float2 v; v.x = xr[0]; v.y = xi[0]; buf[P(t)] = v; }
#pragma unroll
    for (int r = 1; r < 16; ++r) {
        float2 w = tw4096[r * 256 + t];
        float yr = xr[PERM(r)], yi = xi[PERM(r)];
        cmul(yr, yi, w.x, w.y);
        float2 v; v.x = yr; v.y = yi;
        buf[P(t + 256 * r)] = v;
    }
    __syncthreads();

    // ---- Phase B: fwd L=256
    int g = t >> 4, j = t & 15;
    int base = g * 256 + j;
#pragma unroll
    for (int r = 0; r < 16; ++r) {
        float2 v = buf[P(base + 16 * r)];
        xr[r] = v.x; xi[r] = v.y;
    }
    dft16<-1>(xr, xi);
    { float2 v; v.x = xr[0]; v.y = xi[0]; buf[P(base)] = v; }
#pragma unroll
    for (int r = 1; r < 16; ++r) {
        float2 w = tw256[r * 16 + j];
        float yr = xr[PERM(r)], yi = xi[PERM(r)];
        cmul(yr, yi, w.x, w.y);
        float2 v; v.x = yr; v.y = yi;
        buf[P(base + 16 * r)] = v;
    }
    __syncthreads();

    // ---- Phase C: fwd L=16 (j=0, no twiddle) + pointwise*V + inv L=16, regs
    {
        int mb = 16 * t;
#pragma unroll
        for (int r = 0; r < 16; ++r) {
            float2 v = buf[P(mb + r)];
            xr[r] = v.x; xi[r] = v.y;
        }
        dft16<-1>(xr, xi);
        float yr2[16], yi2[16];
        const float4* Vv = (const float4*)(V2 + mb);
#pragma unroll
        for (int h = 0; h < 8; ++h) {
            float4 vv = Vv[h];
            int r = 2 * h;
            float ar = xr[PERM(r)], ai = xi[PERM(r)];
            yr2[r] = ar * vv.x - ai * vv.y;
            yi2[r] = ar * vv.y + ai * vv.x;
            r = 2 * h + 1;
            ar = xr[PERM(r)]; ai = xi[PERM(r)];
            yr2[r] = ar * vv.z - ai * vv.w;
            yi2[r] = ar * vv.w + ai * vv.z;
        }
        dft16<1>(yr2, yi2);
#pragma unroll
        for (int r = 0; r < 16; ++r) {
            float2 v; v.x = yr2[PERM(r)]; v.y = yi2[PERM(r)];
            buf[P(mb + r)] = v;
        }
    }
    __syncthreads();

    // ---- Phase D: inv L=256
#pragma unroll
    for (int r = 0; r < 16; ++r) {
        float2 v = buf[P(base + 16 * r)];
        xr[r] = v.x; xi[r] = v.y;
    }
#pragma unroll
    for (int r = 1; r < 16; ++r) {
        float2 w = tw256[r * 16 + j];
        cmulc(xr[r], xi[r], w.x, w.y);
    }
    dft16<1>(xr, xi);
#pragma unroll
    for (int r = 0; r < 16; ++r) {
        float2 v; v.x = xr[PERM(r)]; v.y = xi[PERM(r)];
        buf[P(base + 16 * r)] = v;
    }
    __syncthreads();

    // ---- Phase E: inv L=4096, pruned output (r<8) stored straight to global
#pragma unroll
    for (int r = 0; r < 16; ++r) {
        float2 v = buf[P(t + 256 * r)];
        xr[r] = v.x; xi[r] = v.y;
    }
#pragma unroll
    for (int r = 1; r < 16; ++r) {
        float2 w = tw4096[r * 256 + t];
        cmulc(xr[r], xi[r], w.x, w.y);
    }
    dft16_layer1<1>(xr, xi);
    dft16_twiddle<1>(xr, xi);
    float* ob = out + ((size_t)b * N_) * E_ + e0;
#pragma unroll
    for (int k1 = 0; k1 < 4; ++k1) {
        float a0r = xr[4 * k1],     a0i = xi[4 * k1];
        float a1r = xr[4 * k1 + 1], a1i = xi[4 * k1 + 1];
        float a2r = xr[4 * k1 + 2], a2i = xi[4 * k1 + 2];
        float a3r = xr[4 * k1 + 3], a3i = xi[4 * k1 + 3];
        float t0r = a0r + a2r, t0i = a0i + a2i;
        float t1r = a0r - a2r, t1i = a0i - a2i;
        float t2r = a1r + a3r, t2i = a1i + a3i;
        float t3r = a1r - a3r, t3i = a1i - a3i;
        // sg=+1: X0 = t0+t2 ; X1 = (t1r - t3i, t1i + t3r)
        float2 v0; v0.x = t0r + t2r; v0.y = t0i + t2i;           // r = k1
        float2 v1; v1.x = t1r - t3i; v1.y = t1i + t3r;           // r = k1+4
        *(float2*)(ob + (size_t)(t + 256 * k1) * E_)       = v0;
        *(float2*)(ob + (size_t)(t + 256 * (k1 + 4)) * E_) = v1;
    }
}

// ---------------- fallback (ws too small): direct fp32 dot -------------------
__global__ __launch_bounds__(256) void naive_toep(const float* __restrict__ x,
                                                  const float* __restrict__ pos,
                                                  const float* __restrict__ zero,
                                                  const float* __restrict__ neg,
                                                  float* __restrict__ out) {
    int bid = blockIdx.x;
    int e   = (bid & 3) * 256 + threadIdx.x;
    int k   = (bid >> 2) & (N_ - 1);
    int b   = bid >> 13;
    float zv = zero[0];
    float acc = 0.f;
    const float* xb = x + (size_t)b * N_ * E_ + e;
    for (int jj = 0; jj < N_; ++jj) {
        float c = (jj < k) ? pos[k - jj - 1] : (jj == k) ? zv : neg[N_ - 1 - jj + k];
        acc += c * xb[(size_t)jj * E_];
    }
    out[((size_t)(b * N_ + k)) * E_ + e] = acc;
}

extern "C" void kernel_launch(void* const* d_in, const int* in_sizes, int n_in,
                              void* d_out, int out_size, void* d_ws, size_t ws_size,
                              hipStream_t stream) {
    const float* x    = (const float*)d_in[0];
    const float* pos  = (const float*)d_in[1];
    const float* zero = (const float*)d_in[2];
    const float* neg  = (const float*)d_in[3];
    float* out = (float*)d_out;

    const size_t needX = (size_t)B_ * E_ * N_ * sizeof(unsigned short);   // 32 MiB
    const size_t need  = needX + (3 * (size_t)NF + 256) * sizeof(float2);
    if (ws_size >= need) {
        unsigned short* xT = (unsigned short*)d_ws;
        float2* tw2    = (float2*)((char*)d_ws + needX);
        float2* V2     = tw2 + NF;
        float2* tw4096 = V2 + NF;
        float2* tw256  = tw4096 + NF;
        build_tw<<<17, 256, 0, stream>>>(tw2, tw4096, tw256);
        transpose_x<<<dim3(16, 32, 8), 256, 0, stream>>>(x, xT);
        build_V<<<1, 256, 0, stream>>>(pos, zero, neg, tw2, V2);
        fft_conv<<<4096, 256, 0, stream>>>(xT, tw4096, tw256, V2, out);
    } else {
        naive_toep<<<65536, 256, 0, stream>>>(x, pos, zero, neg, out);
    }
}